// Round 3
// baseline (23.422 us; speedup 1.0000x reference)
//
#include <hip/hip_runtime.h>
#include <math.h>

#define N_Q 2048
#define M_K 1024
#define DIN 128
#define DK  64

// ---------------------------------------------------------------------------
// Kernel 1: Qp = q @ W^T  (row-major [N_Q][DK]),  KpT = (k @ W^T)^T  ([DK][M_K]),
//           qn2[n] = ||Qp[n]||^2,  kn2[m] = ||Kp[m]||^2
// One wave per row. W staged in LDS, stride DIN+4 floats -> b128-aligned.
// ---------------------------------------------------------------------------
__global__ __launch_bounds__(256) void proj_kernel(
    const float* __restrict__ q, const float* __restrict__ k,
    const float* __restrict__ W, float* __restrict__ Qp,
    float* __restrict__ KpT, float* __restrict__ qn2, float* __restrict__ kn2)
{
    __shared__ float W_lds[DK][DIN + 4];   // stride 132
    __shared__ float row_lds[4][DIN];
    const int tx = threadIdx.x;

    // cooperative load W: 2048 float4s, 8 per thread
    const float4* W4 = (const float4*)W;
    #pragma unroll
    for (int i = 0; i < 8; ++i) {
        int idx = tx + i * 256;            // float4 index
        float4 v = W4[idx];
        int r = idx >> 5, c = (idx & 31) * 4;
        *(float4*)&W_lds[r][c] = v;
    }

    const int wave = tx >> 6, lane = tx & 63;
    const int row  = blockIdx.x * 4 + wave;            // 0..3071
    const float* src = (row < N_Q) ? (q + (size_t)row * DIN)
                                   : (k + (size_t)(row - N_Q) * DIN);
    row_lds[wave][lane]      = src[lane];
    row_lds[wave][lane + 64] = src[lane + 64];
    __syncthreads();

    float acc = 0.f;
    #pragma unroll
    for (int d = 0; d < DIN; d += 4) {
        float4 wv = *(const float4*)&W_lds[lane][d];
        float4 rv = *(const float4*)&row_lds[wave][d];
        acc = fmaf(wv.x, rv.x, acc);
        acc = fmaf(wv.y, rv.y, acc);
        acc = fmaf(wv.z, rv.z, acc);
        acc = fmaf(wv.w, rv.w, acc);
    }

    // wave-reduce sum of squares -> norm^2 of the projected row
    float sq = acc * acc;
    #pragma unroll
    for (int off = 32; off >= 1; off >>= 1)
        sq += __shfl_xor(sq, off, 64);

    if (row < N_Q) {
        Qp[(size_t)row * DK + lane] = acc;
        if (lane == 0) qn2[row] = sq;
    } else {
        const int m = row - N_Q;
        KpT[(size_t)lane * M_K + m] = acc;
        if (lane == 0) kn2[m] = sq;
    }
}

// ---------------------------------------------------------------------------
// Kernel 2: 256 blocks x 1024 threads (16 waves; ~40 VGPR -> 2 blocks/CU
// = 8 waves/SIMD). Block owns 8 q-rows x all 1024 m.
// Thread layout: rg = tx>>8 (4 row-groups x 2 rows), cg = tx&255 (4 cols).
// Thread tile 2x4: per d -> 1 uniform ds_read_b64 (q pair) + 1 coalesced
// global dwordx4 (KpT, L1/L2-resident) + 8 FMA.
// Row-groups re-read the same KpT d-slices -> L1 hits; per-block L2 traffic
// stays 256 KB (64 MB total ~ 1.9 us at L2 BW).
// Fused: dist^2 -> score -> row softmax (shuffle + LDS reduce over 4 waves).
// ---------------------------------------------------------------------------
__global__ __launch_bounds__(1024) void score_kernel(
    const float* __restrict__ Qp, const float* __restrict__ KpT,
    const float* __restrict__ qn2, const float* __restrict__ kn2,
    float* __restrict__ out)
{
    __shared__ float qpT[DK][8];          // d-major: 8 row-values per d
    __shared__ float qn2s[8];
    __shared__ float redmax[8][4];
    __shared__ float redsum[8][4];

    const int tx = threadIdx.x;           // 0..1023
    const int n0 = blockIdx.x * 8;
    const int rg = tx >> 8;               // 0..3  (rows 2rg, 2rg+1)
    const int cg = tx & 255;              // 0..255 (cols 4cg..4cg+3)
    const int lane = tx & 63;
    const int wInRow = (tx >> 6) & 3;     // which of the 4 waves spanning cols

    if (tx < 512) {
        int d = tx >> 3, r = tx & 7;
        qpT[d][r] = Qp[(size_t)(n0 + r) * DK + d];
    }
    if (tx < 8) qn2s[tx] = qn2[n0 + tx];
    __syncthreads();

    float acc[2][4];
    #pragma unroll
    for (int r = 0; r < 2; ++r)
        #pragma unroll
        for (int i = 0; i < 4; ++i) acc[r][i] = 0.f;

    const float4* K4 = (const float4*)KpT;
    #pragma unroll 4
    for (int d = 0; d < DK; ++d) {
        float4 kv = K4[d * (M_K / 4) + cg];
        float2 qv = *(const float2*)&qpT[d][rg * 2];
        float kvv[4] = {kv.x, kv.y, kv.z, kv.w};
        #pragma unroll
        for (int i = 0; i < 4; ++i) {
            acc[0][i] = fmaf(qv.x, kvv[i], acc[0][i]);
            acc[1][i] = fmaf(qv.y, kvv[i], acc[1][i]);
        }
    }

    // scores: s = -0.5*sqrt(max(qn2 + kn2 - 2*dot, 0))
    float4 kv2 = ((const float4*)kn2)[cg];
    float kn2a[4] = {kv2.x, kv2.y, kv2.z, kv2.w};
    #pragma unroll
    for (int r = 0; r < 2; ++r) {
        float qn = qn2s[rg * 2 + r];
        #pragma unroll
        for (int i = 0; i < 4; ++i) {
            float d2 = fmaxf(fmaf(-2.f, acc[r][i], qn + kn2a[i]), 0.f);
            acc[r][i] = -0.5f * sqrtf(d2);
        }
    }

    // row max: 4 waves cover each row's 1024 cols
    #pragma unroll
    for (int r = 0; r < 2; ++r) {
        float m = fmaxf(fmaxf(acc[r][0], acc[r][1]), fmaxf(acc[r][2], acc[r][3]));
        #pragma unroll
        for (int off = 32; off >= 1; off >>= 1)
            m = fmaxf(m, __shfl_xor(m, off, 64));
        if (lane == 0) redmax[rg * 2 + r][wInRow] = m;
    }
    __syncthreads();

    float mx[2];
    #pragma unroll
    for (int r = 0; r < 2; ++r) {
        const float* rm = redmax[rg * 2 + r];
        mx[r] = fmaxf(fmaxf(rm[0], rm[1]), fmaxf(rm[2], rm[3]));
    }

    // exp + row sum
    #pragma unroll
    for (int r = 0; r < 2; ++r) {
        float t = 0.f;
        #pragma unroll
        for (int i = 0; i < 4; ++i) {
            acc[r][i] = __expf(acc[r][i] - mx[r]);
            t += acc[r][i];
        }
        #pragma unroll
        for (int off = 32; off >= 1; off >>= 1)
            t += __shfl_xor(t, off, 64);
        if (lane == 0) redsum[rg * 2 + r][wInRow] = t;
    }
    __syncthreads();

    #pragma unroll
    for (int r = 0; r < 2; ++r) {
        const float* rs = redsum[rg * 2 + r];
        float inv = 1.0f / (rs[0] + rs[1] + rs[2] + rs[3]);
        float4 o = make_float4(acc[r][0] * inv, acc[r][1] * inv,
                               acc[r][2] * inv, acc[r][3] * inv);
        ((float4*)out)[(size_t)(n0 + rg * 2 + r) * (M_K / 4) + cg] = o;
    }
}

extern "C" void kernel_launch(void* const* d_in, const int* in_sizes, int n_in,
                              void* d_out, int out_size, void* d_ws, size_t ws_size,
                              hipStream_t stream)
{
    const float* q = (const float*)d_in[0];
    const float* k = (const float*)d_in[1];
    const float* W = (const float*)d_in[2];
    float* out = (float*)d_out;

    // ws layout (floats): Qp[2048*64] | KpT[64*1024] | qn2[2048] | kn2[1024]
    float* Qp  = (float*)d_ws;
    float* KpT = Qp + (size_t)N_Q * DK;
    float* qn2 = KpT + (size_t)DK * M_K;
    float* kn2 = qn2 + N_Q;

    proj_kernel<<<(N_Q + M_K) / 4, 256, 0, stream>>>(q, k, W, Qp, KpT, qn2, kn2);
    score_kernel<<<N_Q / 8, 1024, 0, stream>>>(Qp, KpT, qn2, kn2, out);
}